// Round 11
// baseline (417.782 us; speedup 1.0000x reference)
//
#include <hip/hip_runtime.h>

typedef __bf16 bf16;
typedef __bf16 bf16x4 __attribute__((ext_vector_type(4)));
typedef __bf16 bf16x8 __attribute__((ext_vector_type(8)));
typedef float f32x4 __attribute__((ext_vector_type(4)));

constexpr int BATCH = 32;
constexpr int SEQ   = 1024;
constexpr int CDIM  = 768;
constexpr int ROWS  = BATCH * SEQ;   // 32768
constexpr int QKVC  = 3 * CDIM;      // 2304

// ---- workspace layout (bytes), ~273.3 MB total ----
constexpr size_t oWqT = 0;                                    // bf16 WqkvT [2304][768]
constexpr size_t oWpT = oWqT + (size_t)QKVC * CDIM * 2;       // bf16 WprojT [768][768]
constexpr size_t oQKV = oWpT + (size_t)CDIM * CDIM * 2;       // bf16 qkv [32768][2304]
constexpr size_t oS   = oQKV + (size_t)ROWS * QKVC * 2;       // bf16 S [32][1024][1024]
constexpr size_t oVT  = oS   + (size_t)BATCH * SEQ * SEQ * 2; // bf16 VT [32][768][1024]
constexpr size_t oInv = oVT  + (size_t)BATCH * CDIM * SEQ * 2;// f32 invsum [32768]
constexpr size_t oAO  = oQKV; // attn_out aliases qkv (q/k dead after QK^T)
constexpr size_t oXB  = oS;   // bf16(x) aliases S (dead before QK^T writes S)
constexpr size_t oPart= oWqT; // f32 partial[32768][4] aliases WqT (dead after qkv)

__device__ __forceinline__ void gld_lds16(const void* g, void* l) {
  __builtin_amdgcn_global_load_lds(
      (const __attribute__((address_space(1))) unsigned int*)g,
      (__attribute__((address_space(3))) unsigned int*)l,
      16, 0, 0);
}

// ---------- x fp32 -> bf16 ----------
__global__ __launch_bounds__(256) void f2b_kernel(const float* __restrict__ x,
                                                  bf16* __restrict__ y) {
  int i = blockIdx.x * blockDim.x + threadIdx.x;
  const float* p = x + (size_t)i * 8;
  float4 a = *(const float4*)p;
  float4 b = *(const float4*)(p + 4);
  bf16x8 o;
  o[0]=(bf16)a.x; o[1]=(bf16)a.y; o[2]=(bf16)a.z; o[3]=(bf16)a.w;
  o[4]=(bf16)b.x; o[5]=(bf16)b.y; o[6]=(bf16)b.z; o[7]=(bf16)b.w;
  *(bf16x8*)(y + (size_t)i * 8) = o;
}

// ---------- weight transpose+convert (tiled): T[n][k] = bf16(W[k][n]) ----------
__global__ __launch_bounds__(256) void wt_kernel(const float* __restrict__ W,
                                                 bf16* __restrict__ T, int N) {
  __shared__ float t[32][33];
  int k0 = blockIdx.x * 32, n0 = blockIdx.y * 32;
  int tx = threadIdx.x & 31, ty = threadIdx.x >> 5; // 32 x 8
  #pragma unroll
  for (int i = 0; i < 4; ++i)
    t[ty + i * 8][tx] = W[(size_t)(k0 + ty + i * 8) * N + n0 + tx];
  __syncthreads();
  #pragma unroll
  for (int i = 0; i < 4; ++i)
    T[(size_t)(n0 + ty + i * 8) * 768 + k0 + tx] = (bf16)t[tx][ty + i * 8];
}

// ---------- finish: inv[row] = 1 / sum_nt partial[row][nt] ----------
__global__ __launch_bounds__(256) void finish_kernel(const float* __restrict__ partial,
                                                     float* __restrict__ inv) {
  int i = blockIdx.x * 256 + threadIdx.x;
  float4 p = *(const float4*)(partial + (size_t)i * 4);
  inv[i] = 1.0f / (p.x + p.y + p.z + p.w);
}

// ======== 256x256 8-wave NT GEMM, 2-iter-deep counted pipeline (m201-class) ======
// Iter = K-tiles {T,T+1}; buf0=T(even), buf1=T+1. 4 quadrant-phases/tile.
// Region free-times: buf.A free after its tile's P2; buf.B after P3.
// Stage slots:  P1: B0,B1(T+1)->buf1.B   P3/P4: A0,A1(T+2)->buf0.A
//               P5/P6: B0,B1(T+2)->buf0.B  P7/P8: A0,A1(T+3)->buf1.A
// Every stage separated from its victim's last read by a barrier (P1/P3/P5/P7).
// Counted waits (outstanding-stack derived; per-wave drain BEFORE barrier):
//   P1: vmcnt(6)  P3: vmcnt(8)  P5: vmcnt(6) [final iter: 2]  P7: vmcnt(8) [final: 0]
// Cover: every load 4-6 phases (~1000-1500 cyc) > 900-cyc HBM latency.
// T2 swizzle (rule 21): linear LDS dest, global chunk (tid&7)^(sr&7),
// read byte kb^((row&7)<<4). nkt must be EVEN and >=4 (12 or 16 here).

#define DSRD_A(dst_, qm_) do {                                                   \
  _Pragma("unroll")                                                              \
  for (int i_ = 0; i_ < 4; ++i_) {                                               \
    const int row_ = wm * 128 + (qm_) * 64 + i_ * 16 + lr;                       \
    const char* rb_ = (const char*)Acur + row_ * 128;                            \
    dst_[i_][0] = *(const bf16x8*)(rb_ + ((0  + kb0) ^ swz));                    \
    dst_[i_][1] = *(const bf16x8*)(rb_ + ((64 + kb0) ^ swz));                    \
  }                                                                              \
} while (0)

#define DSRD_B(dst_, qn_) do {                                                   \
  _Pragma("unroll")                                                              \
  for (int j_ = 0; j_ < 2; ++j_) {                                               \
    const int row_ = wn * 64 + (qn_) * 32 + j_ * 16 + lr;                        \
    const char* rb_ = (const char*)Bcur + row_ * 128;                            \
    dst_[j_][0] = *(const bf16x8*)(rb_ + ((0  + kb0) ^ swz));                    \
    dst_[j_][1] = *(const bf16x8*)(rb_ + ((64 + kb0) ^ swz));                    \
  }                                                                              \
} while (0)

#define STG_A(buf_, kt_, h_) do {                                                \
  gld_lds16(Ast + (size_t)((h_) * 128 +  0) * lda + (size_t)(kt_) * 64,          \
            &LDSB[(buf_)][((h_) * 2 + 0) * 4096 + wv * 512]);                    \
  gld_lds16(Ast + (size_t)((h_) * 128 + 64) * lda + (size_t)(kt_) * 64,          \
            &LDSB[(buf_)][((h_) * 2 + 1) * 4096 + wv * 512]);                    \
} while (0)

#define STG_B(buf_, kt_, h_) do {                                                \
  gld_lds16(Bst + (size_t)((h_) * 128 +  0) * ldb + (size_t)(kt_) * 64,          \
            &LDSB[2 + (buf_)][((h_) * 2 + 0) * 4096 + wv * 512]);                \
  gld_lds16(Bst + (size_t)((h_) * 128 + 64) * ldb + (size_t)(kt_) * 64,          \
            &LDSB[2 + (buf_)][((h_) * 2 + 1) * 4096 + wv * 512]);                \
} while (0)

#define MMA16(a_, b_, mo_, no_) do {                                             \
  asm volatile("s_waitcnt lgkmcnt(0)" ::: "memory");                             \
  __builtin_amdgcn_sched_barrier(0);                                             \
  __builtin_amdgcn_s_setprio(1);                                                 \
  _Pragma("unroll")                                                              \
  for (int ks_ = 0; ks_ < 2; ++ks_)                                              \
    _Pragma("unroll")                                                            \
    for (int i_ = 0; i_ < 4; ++i_)                                               \
      _Pragma("unroll")                                                          \
      for (int j_ = 0; j_ < 2; ++j_)                                             \
        acc[(mo_) + i_][(no_) + j_] =                                            \
            __builtin_amdgcn_mfma_f32_16x16x32_bf16(a_[i_][ks_], b_[j_][ks_],    \
                acc[(mo_) + i_][(no_) + j_], 0, 0, 0);                           \
  __builtin_amdgcn_s_setprio(0);                                                 \
} while (0)

#define PIN() __builtin_amdgcn_sched_barrier(0)
#define BAR() __builtin_amdgcn_s_barrier()
#define WAITV(n_) asm volatile("s_waitcnt vmcnt(" #n_ ")" ::: "memory")

template<bool OUT_BF16, bool HAS_BIAS, bool FUSE_EXP, bool TR_V>
__global__ __launch_bounds__(512, 2) void gemm256d(
    const bf16* __restrict__ Ap, const bf16* __restrict__ Bp, void* __restrict__ Cp,
    int K, int lda, int ldb, int ldc, int ntm, int ntn,
    long sA, long sB, long sC,
    float scale, const float* __restrict__ bias, float* __restrict__ partial,
    bf16* __restrict__ vtout)
{
  __shared__ __align__(16) bf16 LDSB[4][256 * 64]; // [Abuf0,Abuf1,Bbuf0,Bbuf1]
  const int tid  = threadIdx.x;
  const int lane = tid & 63;
  const int wv   = tid >> 6;      // 0..7
  const int wm   = wv >> 2;       // 0..1  (128-row half)
  const int wn   = wv & 3;        // 0..3  (64-col strip)

  const int total = (int)gridDim.x;
  const int chunk = total >> 3;
  const int bid   = (int)blockIdx.x;
  int sbid = (bid & 7) * chunk + (bid >> 3);
  const int pb = ntm * ntn;
  const int z  = sbid / pb;  sbid -= z * pb;
  const int mt = sbid / ntn;
  const int nt = sbid - mt * ntn;
  const int m0 = mt * 256, n0 = nt * 256;

  const bf16* A = Ap + (size_t)z * sA;
  const bf16* B = Bp + (size_t)z * sB;

  const int sr  = tid >> 3;
  const int gch = (tid & 7) ^ (sr & 7);
  const bf16* Ast = A + (size_t)(m0 + sr) * lda + gch * 8;
  const bf16* Bst = B + (size_t)(n0 + sr) * ldb + gch * 8;

  const int lr  = lane & 15;
  const int hi  = lane >> 4;
  const int swz = (lane & 7) << 4;
  const int kb0 = hi * 16;

  f32x4 acc[8][4] = {};
  const int nkt = K >> 6;   // even, >= 4

  // prologue: A(0), B(0), A(1)  (B(1) staged at iter-0 P1)
  STG_A(0, 0, 0); STG_A(0, 0, 1);
  STG_B(0, 0, 0); STG_B(0, 0, 1);
  STG_A(1, 1, 0); STG_A(1, 1, 1);

  bf16x8 a0[4][2], a1[4][2], b0[2][2], b1[2][2];
  for (int T = 0; T < nkt; T += 2) {
    const bool sa = (T + 2 < nkt);
    {
      const bf16* Acur = LDSB[0];
      const bf16* Bcur = LDSB[2];
      // P1 — needs A0(T),B0(T); leaves {A1(T+1),A0(T+1),B1(T)} in flight
      WAITV(6); BAR(); PIN();
      DSRD_A(a0, 0); DSRD_B(b0, 0);
      PIN();
      STG_B(1, T + 1, 0); STG_B(1, T + 1, 1);   // buf1.B free since prev P7
      MMA16(a0, b0, 0, 0);
      // P2
      DSRD_A(a1, 1); PIN();
      MMA16(a1, b0, 4, 0);
      // P3 — needs B1(T)
      WAITV(8); BAR(); PIN();
      DSRD_B(b1, 1); PIN();
      if (sa) STG_A(0, T + 2, 0);               // buf0.A free after P2
      MMA16(a1, b1, 4, 2);
      // P4
      if (sa) STG_A(0, T + 2, 1);
      PIN();
      MMA16(a0, b1, 0, 2);
    }
    {
      const bf16* Acur = LDSB[1];
      const bf16* Bcur = LDSB[3];
      // P5 — needs A0(T+1),B0(T+1)
      if (sa) { WAITV(6); } else { WAITV(2); }
      BAR(); PIN();
      DSRD_A(a0, 0); DSRD_B(b0, 0);
      PIN();
      if (sa) STG_B(0, T + 2, 0);               // buf0.B free after P3
      MMA16(a0, b0, 0, 0);
      // P6
      DSRD_A(a1, 1); PIN();
      if (sa) STG_B(0, T + 2, 1);
      MMA16(a1, b0, 4, 0);
      // P7 — needs B1(T+1) (staged this iter P1)
      if (sa) { WAITV(8); } else { WAITV(0); }
      BAR(); PIN();
      DSRD_B(b1, 1); PIN();
      if (sa) STG_A(1, T + 3, 0);               // buf1.A free after P6
      MMA16(a1, b1, 4, 2);
      // P8
      if (sa) STG_A(1, T + 3, 1);
      PIN();
      MMA16(a0, b1, 0, 2);
    }
  }

  // epilogue: C/D layout col=lane&15, row=(lane>>4)*4+reg (m89-verified)
  if (TR_V && nt >= 6) {
    bf16* tile = LDSB[0];
    __syncthreads();
    #pragma unroll
    for (int mf = 0; mf < 8; ++mf) {
      #pragma unroll
      for (int nf = 0; nf < 4; ++nf) {
        const int lm = wm * 128 + mf * 16 + hi * 4;
        const int lc = wn * 64 + nf * 16 + lr;
        bf16x4 w;
        #pragma unroll
        for (int r = 0; r < 4; ++r) {
          float v = acc[mf][nf][r] * scale;
          if (HAS_BIAS) v += bias[n0 + lc];
          w[r] = (bf16)v;
        }
        *(bf16x4*)((char*)tile + lc * 512 + ((lm * 2) ^ ((lc & 7) << 4))) = w;
      }
    }
    __syncthreads();
    const int bz = m0 >> 10;
    const int mb = m0 & 1023;
    bf16* dst = vtout + ((size_t)bz * CDIM + (n0 - 2 * CDIM)) * SEQ + mb;
    #pragma unroll
    for (int it = 0; it < 16; ++it) {
      const int c  = (tid >> 5) + it * 16;
      const int ch = tid & 31;
      bf16x8 vv = *(const bf16x8*)((const char*)tile + c * 512 + ((ch * 16) ^ ((c & 7) << 4)));
      *(bf16x8*)(dst + (size_t)c * SEQ + ch * 8) = vv;
    }
  } else if (FUSE_EXP) {
    float rs[8][4];
    #pragma unroll
    for (int mf = 0; mf < 8; ++mf)
      #pragma unroll
      for (int r = 0; r < 4; ++r) rs[mf][r] = 0.f;
    #pragma unroll
    for (int mf = 0; mf < 8; ++mf)
      #pragma unroll
      for (int nf = 0; nf < 4; ++nf)
        #pragma unroll
        for (int r = 0; r < 4; ++r) {
          int gm = m0 + wm * 128 + mf * 16 + hi * 4 + r;
          int gn = n0 + wn * 64 + nf * 16 + lr;
          float e = __expf(acc[mf][nf][r] * scale);
          ((bf16*)Cp)[(size_t)z * sC + (size_t)gm * ldc + gn] = (bf16)e;
          rs[mf][r] += e;
        }
    float* sl = (float*)LDSB;
    __syncthreads();
    #pragma unroll
    for (int mf = 0; mf < 8; ++mf)
      #pragma unroll
      for (int r = 0; r < 4; ++r) {
        float s = rs[mf][r];
        s += __shfl_xor(s, 1); s += __shfl_xor(s, 2);
        s += __shfl_xor(s, 4); s += __shfl_xor(s, 8);
        if (lr == 0)
          sl[wn * 256 + wm * 128 + mf * 16 + hi * 4 + r] = s;
      }
    __syncthreads();
    if (tid < 256) {
      float s = sl[tid] + sl[256 + tid] + sl[512 + tid] + sl[768 + tid];
      partial[((size_t)z * SEQ + m0 + tid) * 4 + nt] = s;
    }
  } else {
    #pragma unroll
    for (int mf = 0; mf < 8; ++mf) {
      #pragma unroll
      for (int nf = 0; nf < 4; ++nf) {
        #pragma unroll
        for (int r = 0; r < 4; ++r) {
          int gm = m0 + wm * 128 + mf * 16 + hi * 4 + r;
          int gn = n0 + wn * 64 + nf * 16 + lr;
          float v = acc[mf][nf][r] * scale;
          if (HAS_BIAS) v += bias[gn];
          if (OUT_BF16) ((bf16*)Cp)[(size_t)z * sC + (size_t)gm * ldc + gn] = (bf16)v;
          else          ((float*)Cp)[(size_t)z * sC + (size_t)gm * ldc + gn] = v;
        }
      }
    }
  }
}

// ============ 128x128 4-wave NT GEMM — r10 engine (937-TF, 3 blocks/CU) ==========
template<bool OUT_BF16, bool HAS_BIAS, bool ROW_SCALE>
__global__ __launch_bounds__(256, 3) void gemm128(
    const bf16* __restrict__ Ap, const bf16* __restrict__ Bp, void* __restrict__ Cp,
    int K, int lda, int ldb, int ldc, int ntm, int ntn,
    long sA, long sB, long sC,
    float scale, const float* __restrict__ rowScale, long sRS,
    const float* __restrict__ bias)
{
  __shared__ __align__(16) bf16 LDS[128 * 128];   // 32 KiB: As | Bs
  bf16* As = LDS;
  bf16* Bs = LDS + 128 * 64;
  const int tid  = threadIdx.x;
  const int lane = tid & 63;
  const int wv   = tid >> 6;
  const int wm   = wv >> 1;
  const int wn   = wv & 1;

  const int total = (int)gridDim.x;
  const int chunk = total >> 3;
  const int bid   = (int)blockIdx.x;
  int sbid = (bid & 7) * chunk + (bid >> 3);
  const int pb = ntm * ntn;
  const int z  = sbid / pb;  sbid -= z * pb;
  const int mt = sbid / ntn;
  const int nt = sbid - mt * ntn;
  const int m0 = mt * 128, n0 = nt * 128;

  const bf16* A = Ap + (size_t)z * sA;
  const bf16* B = Bp + (size_t)z * sB;

  const int sr  = tid >> 3;
  const int gch = (tid & 7) ^ (sr & 7);
  const bf16* Ast = A + (size_t)(m0 + sr) * lda + gch * 8;
  const bf16* Bst = B + (size_t)(n0 + sr) * ldb + gch * 8;

  const int lr  = lane & 15;
  const int hi  = lane >> 4;
  const int swz = (lane & 7) << 4;
  const int kb0 = hi * 16;

  f32x4 acc[4][4] = {};

  for (int kt = 0; kt < K; kt += 64) {
    #pragma unroll
    for (int it = 0; it < 4; ++it) {
      gld_lds16(Ast + (size_t)(it * 32) * lda + kt, As + it * 2048 + wv * 512);
      gld_lds16(Bst + (size_t)(it * 32) * ldb + kt, Bs + it * 2048 + wv * 512);
    }
    __syncthreads();
    #pragma unroll
    for (int ks = 0; ks < 2; ++ks) {
      bf16x8 af[4], bfr[4];
      #pragma unroll
      for (int i = 0; i < 4; ++i) {
        const int rm = wm * 64 + i * 16 + lr;
        af[i]  = *(const bf16x8*)((const char*)As + rm * 128 + ((ks * 64 + kb0) ^ swz));
        const int rn = wn * 64 + i * 16 + lr;
        bfr[i] = *(const bf16x8*)((const char*)Bs + rn * 128 + ((ks * 64 + kb0) ^ swz));
      }
      #pragma unroll
      for (int i = 0; i < 4; ++i)
        #pragma unroll
        for (int j = 0; j < 4; ++j)
          acc[i][j] = __builtin_amdgcn_mfma_f32_16x16x32_bf16(af[i], bfr[j], acc[i][j], 0, 0, 0);
    }
    __syncthreads();
  }

  #pragma unroll
  for (int i = 0; i < 4; ++i) {
    #pragma unroll
    for (int j = 0; j < 4; ++j) {
      #pragma unroll
      for (int r = 0; r < 4; ++r) {
        const int gm = m0 + wm * 64 + i * 16 + hi * 4 + r;
        const int gn = n0 + wn * 64 + j * 16 + lr;
        float v = acc[i][j][r] * scale;
        if (ROW_SCALE) v *= rowScale[(size_t)z * sRS + gm];
        if (HAS_BIAS)  v += bias[gn];
        if (OUT_BF16) ((bf16*)Cp)[(size_t)z * sC + (size_t)gm * ldc + gn] = (bf16)v;
        else          ((float*)Cp)[(size_t)z * sC + (size_t)gm * ldc + gn] = v;
      }
    }
  }
}

extern "C" void kernel_launch(void* const* d_in, const int* in_sizes, int n_in,
                              void* d_out, int out_size, void* d_ws, size_t ws_size,
                              hipStream_t stream) {
  const float* x     = (const float*)d_in[0];
  const float* Wqkv  = (const float*)d_in[1];
  const float* bqkv  = (const float*)d_in[2];
  const float* Wproj = (const float*)d_in[3];
  const float* bproj = (const float*)d_in[4];
  float* out = (float*)d_out;
  char*  ws  = (char*)d_ws;

  bf16*  WqT = (bf16*)(ws + oWqT);
  bf16*  WpT = (bf16*)(ws + oWpT);
  bf16*  qkv = (bf16*)(ws + oQKV);
  bf16*  S   = (bf16*)(ws + oS);
  bf16*  VT  = (bf16*)(ws + oVT);
  float* inv = (float*)(ws + oInv);
  bf16*  AO  = (bf16*)(ws + oAO);
  bf16*  xb  = (bf16*)(ws + oXB);
  float* part= (float*)(ws + oPart);

  const float qk_scale = 1.0f / sqrtf((float)CDIM);

  // 1. conversions / transposes
  f2b_kernel<<<ROWS * CDIM / 8 / 256, 256, 0, stream>>>(x, xb);
  wt_kernel<<<dim3(768 / 32, QKVC / 32), 256, 0, stream>>>(Wqkv, WqT, QKVC);
  wt_kernel<<<dim3(768 / 32, CDIM / 32), 256, 0, stream>>>(Wproj, WpT, CDIM);

  // 2. qkv = xb @ WqT^T + b_qkv (deep 256²); V third (nt>=6) -> VT transposed
  gemm256d<true, true, false, true><<<(ROWS / 256) * (QKVC / 256), 512, 0, stream>>>(
      xb, WqT, qkv, CDIM, CDIM, CDIM, QKVC, ROWS / 256, QKVC / 256,
      0, 0, 0, 1.0f, bqkv, nullptr, VT);

  // 3. S = exp(q @ k^T * scale), fused row-partial sums (deep 256²)
  gemm256d<true, false, true, false><<<BATCH * (SEQ / 256) * (SEQ / 256), 512, 0, stream>>>(
      qkv, qkv + CDIM, S, CDIM, QKVC, QKVC, SEQ, SEQ / 256, SEQ / 256,
      (long)SEQ * QKVC, (long)SEQ * QKVC, (long)SEQ * SEQ, qk_scale, nullptr, part, nullptr);

  // 4. inv = 1/rowsum (4 n-tile partials)
  finish_kernel<<<ROWS / 256, 256, 0, stream>>>(part, inv);

  // 5. attn_out = (expS @ VT^T) * inv[row]  (128² engine, 1536 blocks)
  gemm128<true, false, true><<<BATCH * (SEQ / 128) * (CDIM / 128), 256, 0, stream>>>(
      S, VT, AO, SEQ, SEQ, SEQ, CDIM, SEQ / 128, CDIM / 128,
      (long)SEQ * SEQ, (long)CDIM * SEQ, (long)SEQ * CDIM, 1.0f, inv, SEQ, nullptr);

  // 6. out = attn_out @ WpT^T + b_proj  (128² engine)
  gemm128<false, true, false><<<(ROWS / 128) * (CDIM / 128), 256, 0, stream>>>(
      AO, WpT, out, CDIM, CDIM, CDIM, CDIM, ROWS / 128, CDIM / 128,
      0, 0, 0, 1.0f, nullptr, 0, bproj);
}